// Round 4
// baseline (522.949 us; speedup 1.0000x reference)
//
#include <hip/hip_runtime.h>
#include <hip/hip_bf16.h>

#define LOG2E 1.4426950408889634f

typedef __attribute__((ext_vector_type(8))) short frag_ab;   // 8 bf16 (4 VGPRs)
typedef __attribute__((ext_vector_type(4))) float frag_cd;   // 4 fp32 acc

// fp32 -> bf16 bits, round-to-nearest-even (inputs finite)
__device__ inline short f2bf(float f) {
    union { float f; unsigned u; } v; v.f = f;
    unsigned r = v.u + 0x7fffu + ((v.u >> 16) & 1u);
    return (short)(r >> 16);
}

// Blocks 0..63: W[128][1024] fp32 -> wbf bf16 in MFMA fragment order.
// Block 64: covh[h][p] = f16(cov[h][k]*log2e), p = (k + 16*(h>>5)) & 127
//   (per-row rotation so combine's strided LDS reads are 2-way/free).
__global__ __launch_bounds__(256) void prep_kernel(const float* __restrict__ W,
                                                   const float* __restrict__ cov,
                                                   short* __restrict__ wbf,
                                                   unsigned short* __restrict__ covh) {
    if (blockIdx.x < 64) {
        int g = blockIdx.x * 256 + threadIdx.x;   // 0..16383
        int h = g >> 7;
        int k0 = (g & 127) << 3;
        const float* src = W + h * 1024 + k0;
        float4 w0 = *(const float4*)src;
        float4 w1 = *(const float4*)(src + 4);
        frag_ab af;
        af[0] = f2bf(w0.x); af[1] = f2bf(w0.y); af[2] = f2bf(w0.z); af[3] = f2bf(w0.w);
        af[4] = f2bf(w1.x); af[5] = f2bf(w1.y); af[6] = f2bf(w1.z); af[7] = f2bf(w1.w);
        int c = k0 >> 6, s = (k0 >> 5) & 1, kg = (k0 >> 3) & 3;
        int nt = h >> 4, m = h & 15, lane = kg * 16 + m;
        int dst = (((c * 8 + nt) * 2 + s) * 64 + lane) * 8;
        *(frag_ab*)(wbf + dst) = af;
    } else {
        int t = threadIdx.x;
        int h = t >> 1;
        int k0 = (t & 1) * 64;
        const float* cr = cov + h * 128 + k0;
        int rot = 16 * (h >> 5);
        for (int k = 0; k < 64; ++k) {
            float c = cr[k] * LOG2E;
            union { _Float16 hf; unsigned short us; } cu;
            cu.hf = (_Float16)c;
            int p = (k0 + k + rot) & 127;
            covh[h * 128 + p] = cu.us;
        }
    }
}

// vm[row][h] = sum_k x[row][k]*W[h][k]. Barrier-free, register-pipelined:
// A (x, HBM) prefetched 3 chunks deep; B (wbf, L1/L2-hot fragment order)
// loaded per chunk AFTER the A-prefetch issue so incremental vmcnt waits
// on B never drain the A queue. __launch_bounds__(256,2) -> 256-VGPR budget
// so the 16-frag B array + 4-slot A queue stay in registers.
__global__ __launch_bounds__(256, 2) void proj_kernel(const float* __restrict__ x,
                                                      const short* __restrict__ wbf,
                                                      float* __restrict__ vm) {
    const int tid = threadIdx.x;
    const int lane = tid & 63;
    const int wave = tid >> 6;
    const int m = lane & 15, kg = lane >> 4;
    const long rowbase = ((long)blockIdx.x * 4 + wave) * 16;
    const float* xrow = x + (rowbase + m) * 1024 + kg * 8;
    const char* wb = (const char*)wbf + lane * 16;

    frag_cd acc[8];
#pragma unroll
    for (int nt = 0; nt < 8; ++nt) acc[nt] = (frag_cd){0.f, 0.f, 0.f, 0.f};

    float4 aq[4][4];
#pragma unroll
    for (int pc = 0; pc < 3; ++pc) {
        const float* xn = xrow + pc * 64;
        aq[pc][0] = *(const float4*)(xn);
        aq[pc][1] = *(const float4*)(xn + 4);
        aq[pc][2] = *(const float4*)(xn + 32);
        aq[pc][3] = *(const float4*)(xn + 36);
    }

#pragma unroll
    for (int c = 0; c < 16; ++c) {
        // B loads for this chunk (16 x 1KB coalesced, L1/L2-hot)
        frag_ab bfr[16];
        const char* bc = wb + c * 16384;
#pragma unroll
        for (int f = 0; f < 16; ++f)
            bfr[f] = *(const frag_ab*)(bc + f * 1024);

        // A prefetch 3 chunks ahead (issued after B: vmcnt waits for B
        // leave these outstanding)
        if (c + 3 < 16) {
            const float* xn = xrow + (c + 3) * 64;
            aq[(c + 3) & 3][0] = *(const float4*)(xn);
            aq[(c + 3) & 3][1] = *(const float4*)(xn + 4);
            aq[(c + 3) & 3][2] = *(const float4*)(xn + 32);
            aq[(c + 3) & 3][3] = *(const float4*)(xn + 36);
        }

        float4 a0 = aq[c & 3][0], a1 = aq[c & 3][1];
        float4 a2 = aq[c & 3][2], a3 = aq[c & 3][3];
        frag_ab af0, af1;
        af0[0] = f2bf(a0.x); af0[1] = f2bf(a0.y); af0[2] = f2bf(a0.z); af0[3] = f2bf(a0.w);
        af0[4] = f2bf(a1.x); af0[5] = f2bf(a1.y); af0[6] = f2bf(a1.z); af0[7] = f2bf(a1.w);
        af1[0] = f2bf(a2.x); af1[1] = f2bf(a2.y); af1[2] = f2bf(a2.z); af1[3] = f2bf(a2.w);
        af1[4] = f2bf(a3.x); af1[5] = f2bf(a3.y); af1[6] = f2bf(a3.z); af1[7] = f2bf(a3.w);

#pragma unroll
        for (int nt = 0; nt < 8; ++nt) {
            acc[nt] = __builtin_amdgcn_mfma_f32_16x16x32_bf16(af0, bfr[nt * 2 + 0], acc[nt], 0, 0, 0);
            acc[nt] = __builtin_amdgcn_mfma_f32_16x16x32_bf16(af1, bfr[nt * 2 + 1], acc[nt], 0, 0, 0);
        }
    }

    // C/D: col = lane&15 (=h within tile), row = kg*4 + r
#pragma unroll
    for (int nt = 0; nt < 8; ++nt) {
#pragma unroll
        for (int r = 0; r < 4; ++r) {
            long row = rowbase + kg * 4 + r;
            vm[row * 128 + nt * 16 + m] = acc[nt][r];
        }
    }
}

// out[b,k] = bias[k] + sum_h v[b,h] * exp2(mask[b,h]*c2[h,k]) / sum_k' exp2(...)
// (softmax max-shift cancels exactly; args bounded ~|3.5| so no overflow).
// One WAVE per b (no barriers in the loop). lane (i=lane>>4, j=lane&15):
// owns h in {32i..32i+31}, k in {2j+32s+par}. c2 = f16(cov*log2e) in LDS,
// per-row rotated 16*(h>>5) so the strided b32 reads are 2-way (free).
__global__ __launch_bounds__(256, 4) void combine_kernel(const float* __restrict__ vm,
                                                         const unsigned short* __restrict__ covh,
                                                         const float* __restrict__ bias,
                                                         float* __restrict__ out, int B) {
    __shared__ __align__(16) unsigned short cov_s[128 * 128];   // 32 KB
    const int t = threadIdx.x;

    // stage covh -> LDS once (coalesced float4)
    {
        const float4* cg = (const float4*)covh;
        float4* cl = (float4*)cov_s;
#pragma unroll
        for (int q = 0; q < 8; ++q) cl[q * 256 + t] = cg[q * 256 + t];
    }
    __syncthreads();

    const int lane = t & 63;
    const int wavei = t >> 6;
    const int i = lane >> 4;   // h-block 0..3
    const int j = lane & 15;   // k-lane 0..15

    float biasr[8];
#pragma unroll
    for (int s = 0; s < 4; ++s) {
        float2 bp = *(const float2*)(bias + 2 * j + 32 * s);
        biasr[2 * s] = bp.x; biasr[2 * s + 1] = bp.y;
    }
    int colb[4];
#pragma unroll
    for (int s = 0; s < 4; ++s) colb[s] = ((2 * j + 32 * s + 16 * i) & 127) * 2;

    const char* covb = (const char*)cov_s;
    const int gw = blockIdx.x * 4 + wavei;
    const int nw = gridDim.x * 4;

    for (int b = gw; b < B; b += nw) {
        // prefetch this b's values+mask slices (broadcast across j-lanes)
        const float* vrow = vm + (long)(2 * b) * 128 + 32 * i;
        const float* mrow = vrow + 128;
        float vv[32], mk[32];
#pragma unroll
        for (int q = 0; q < 8; ++q) {
            float4 v4 = *(const float4*)(vrow + 4 * q);
            vv[4 * q] = v4.x; vv[4 * q + 1] = v4.y; vv[4 * q + 2] = v4.z; vv[4 * q + 3] = v4.w;
            float4 m4 = *(const float4*)(mrow + 4 * q);
            mk[4 * q] = m4.x; mk[4 * q + 1] = m4.y; mk[4 * q + 2] = m4.z; mk[4 * q + 3] = m4.w;
        }

        float op[8] = {0.f, 0.f, 0.f, 0.f, 0.f, 0.f, 0.f, 0.f};
#pragma unroll
        for (int tt = 0; tt < 32; ++tt) {
            float mval = mk[tt];
            int rb = (32 * i + tt) * 256;   // row byte offset
            float p[8];
            float ls = 0.f;
#pragma unroll
            for (int s = 0; s < 4; ++s) {
                unsigned cc = *(const unsigned*)(covb + rb + colb[s]);
                union { unsigned u; _Float16 h[2]; } cu; cu.u = cc;
                float c0 = (float)cu.h[0], c1 = (float)cu.h[1];
                float p0 = __builtin_amdgcn_exp2f(mval * c0);
                float p1 = __builtin_amdgcn_exp2f(mval * c1);
                p[2 * s] = p0; p[2 * s + 1] = p1;
                ls += p0 + p1;
            }
            ls += __shfl_xor(ls, 1, 16);
            ls += __shfl_xor(ls, 2, 16);
            ls += __shfl_xor(ls, 4, 16);
            ls += __shfl_xor(ls, 8, 16);
            float w = vv[tt] * __builtin_amdgcn_rcpf(ls);
#pragma unroll
            for (int u = 0; u < 8; ++u) op[u] = fmaf(w, p[u], op[u]);
        }
        // reduce over the 4 i-groups (same k-sets, lanes differ in bits 4-5)
#pragma unroll
        for (int u = 0; u < 8; ++u) {
            op[u] += __shfl_xor(op[u], 16, 64);
            op[u] += __shfl_xor(op[u], 32, 64);
        }
        if (lane < 16) {
            float* ob = out + (long)b * 128;
#pragma unroll
            for (int s = 0; s < 4; ++s) {
                float2 o2;
                o2.x = op[2 * s] + biasr[2 * s];
                o2.y = op[2 * s + 1] + biasr[2 * s + 1];
                *(float2*)(ob + 2 * j + 32 * s) = o2;
            }
        }
    }
}

extern "C" void kernel_launch(void* const* d_in, const int* in_sizes, int n_in,
                              void* d_out, int out_size, void* d_ws, size_t ws_size,
                              hipStream_t stream) {
    const float* x    = (const float*)d_in[0];
    const float* W    = (const float*)d_in[1];
    const float* cov  = (const float*)d_in[2];
    const float* bias = (const float*)d_in[3];
    float* out = (float*)d_out;

    const int B = in_sizes[0] / (2 * 1024);   // 16384

    float* vm  = (float*)d_ws;                             // [2B][128] fp32
    short* wbf = (short*)(vm + (size_t)2 * B * 128);       // [128*1024] bf16 frag order
    unsigned short* covh = (unsigned short*)(wbf + 128 * 1024);   // [128*128] f16 rotated

    prep_kernel<<<65, 256, 0, stream>>>(W, cov, wbf, covh);

    const int blocks = (2 * B) / 64;          // 16 rows/wave, 4 waves/block -> 512
    proj_kernel<<<blocks, 256, 0, stream>>>(x, wbf, vm);

    combine_kernel<<<1024, 256, 0, stream>>>(vm, covh, bias, out, B);
}

// Round 5
// 287.232 us; speedup vs baseline: 1.8206x; 1.8206x over previous
//
#include <hip/hip_runtime.h>
#include <hip/hip_bf16.h>

#define LOG2E 1.4426950408889634f

typedef __attribute__((ext_vector_type(8))) short frag_ab;   // 8 bf16 (4 VGPRs)
typedef __attribute__((ext_vector_type(4))) float frag_cd;   // 4 fp32 acc

// fp32 -> bf16 bits, round-to-nearest-even (inputs finite)
__device__ inline short f2bf(float f) {
    union { float f; unsigned u; } v; v.f = f;
    unsigned r = v.u + 0x7fffu + ((v.u >> 16) & 1u);
    return (short)(r >> 16);
}

// Blocks 0..63: W[128][1024] fp32 -> wbf bf16 in MFMA fragment order:
//   (h,k): c=k>>6, s=(k>>5)&1, kg=(k>>3)&3, j=k&7, nt=h>>4, m=h&15,
//   lane=kg*16+m -> wbf[(((c*8+nt)*2+s)*64+lane)*8 + j]
// Block 64: covh[h][p] = f16(cov[h][k]*log2e), p=(k+16*(h&3))&127
//   (rotation by h&3 so combine's lanes i=h&3 hit disjoint bank groups).
__global__ __launch_bounds__(256) void prep_kernel(const float* __restrict__ W,
                                                   const float* __restrict__ cov,
                                                   short* __restrict__ wbf,
                                                   unsigned short* __restrict__ covh) {
    if (blockIdx.x < 64) {
        int g = blockIdx.x * 256 + threadIdx.x;   // 0..16383
        int h = g >> 7;
        int k0 = (g & 127) << 3;
        const float* src = W + h * 1024 + k0;
        float4 w0 = *(const float4*)src;
        float4 w1 = *(const float4*)(src + 4);
        frag_ab af;
        af[0] = f2bf(w0.x); af[1] = f2bf(w0.y); af[2] = f2bf(w0.z); af[3] = f2bf(w0.w);
        af[4] = f2bf(w1.x); af[5] = f2bf(w1.y); af[6] = f2bf(w1.z); af[7] = f2bf(w1.w);
        int c = k0 >> 6, s = (k0 >> 5) & 1, kg = (k0 >> 3) & 3;
        int nt = h >> 4, m = h & 15, lane = kg * 16 + m;
        int dst = (((c * 8 + nt) * 2 + s) * 64 + lane) * 8;
        *(frag_ab*)(wbf + dst) = af;
    } else {
        int t = threadIdx.x;
        int h = t >> 1;
        int k0 = (t & 1) * 64;
        const float* cr = cov + h * 128 + k0;
        int rot = 16 * (h & 3);
        for (int k = 0; k < 64; ++k) {
            float c = cr[k] * LOG2E;
            union { _Float16 hf; unsigned short us; } cu;
            cu.hf = (_Float16)c;
            int p = (k0 + k + rot) & 127;
            covh[h * 128 + p] = cu.us;
        }
    }
}

// Fused: per block (4 waves), 64 x-rows = 32 b's.
// Phase 1 (per wave, barrier-free): vm[16 rows][128 h] via MFMA.
//   A (x, HBM ~900cyc) prefetched 3 chunks deep in regs;
//   B (wbf, L2-hot frag order) double-buffered in regs (1 chunk ahead).
// acc -> LDS vm_s[wave] -> one __syncthreads -> Phase 2 (per wave): softmax-
// combine its own 8 b's. Softmax max-shift cancels exactly (args |.|<~4).
__global__ __launch_bounds__(256, 2) void fused_kernel(const float* __restrict__ x,
                                                       const short* __restrict__ wbf,
                                                       const unsigned short* __restrict__ covh,
                                                       const float* __restrict__ bias,
                                                       float* __restrict__ out) {
    __shared__ __align__(16) unsigned short cov_s[128 * 128];  // 32 KB
    __shared__ __align__(16) float vm_s[4][128][16];           // 32 KB, [wave][h][row]

    const int tid = threadIdx.x;

    // stage covh -> LDS (issued first; waits drain nothing else)
    {
        const float4* cg = (const float4*)covh;
        float4* cl = (float4*)cov_s;
#pragma unroll
        for (int q = 0; q < 8; ++q) cl[q * 256 + tid] = cg[q * 256 + tid];
    }

    const int lane = tid & 63, wave = tid >> 6;
    const int m = lane & 15, kg = lane >> 4;
    const long rowbase = (long)blockIdx.x * 64 + wave * 16;
    const float* xrow = x + (rowbase + m) * 1024 + kg * 8;
    const char* wb = (const char*)wbf + lane * 16;

    frag_cd acc[8];
#pragma unroll
    for (int nt = 0; nt < 8; ++nt) acc[nt] = (frag_cd){0.f, 0.f, 0.f, 0.f};

    frag_ab bfr[2][16];
    float4 aq[3][4];

    // prologue: B chunk 0, A chunks 0..2
#pragma unroll
    for (int f = 0; f < 16; ++f) bfr[0][f] = *(const frag_ab*)(wb + f * 1024);
#pragma unroll
    for (int pc = 0; pc < 3; ++pc) {
        const float* xn = xrow + pc * 64;
        aq[pc][0] = *(const float4*)(xn);
        aq[pc][1] = *(const float4*)(xn + 4);
        aq[pc][2] = *(const float4*)(xn + 32);
        aq[pc][3] = *(const float4*)(xn + 36);
    }

#pragma unroll
    for (int c = 0; c < 16; ++c) {
        // convert A chunk c (landed: issued 3 chunks ago)
        float4 a0 = aq[c % 3][0], a1 = aq[c % 3][1];
        float4 a2 = aq[c % 3][2], a3 = aq[c % 3][3];
        frag_ab af0, af1;
        af0[0] = f2bf(a0.x); af0[1] = f2bf(a0.y); af0[2] = f2bf(a0.z); af0[3] = f2bf(a0.w);
        af0[4] = f2bf(a1.x); af0[5] = f2bf(a1.y); af0[6] = f2bf(a1.z); af0[7] = f2bf(a1.w);
        af1[0] = f2bf(a2.x); af1[1] = f2bf(a2.y); af1[2] = f2bf(a2.z); af1[3] = f2bf(a2.w);
        af1[4] = f2bf(a3.x); af1[5] = f2bf(a3.y); af1[6] = f2bf(a3.z); af1[7] = f2bf(a3.w);

        // issue next B chunk (reg double-buffer) and A chunk c+3
        if (c < 15) {
            const char* bc = wb + (c + 1) * 16384;
#pragma unroll
            for (int f = 0; f < 16; ++f)
                bfr[(c + 1) & 1][f] = *(const frag_ab*)(bc + f * 1024);
        }
        if (c + 3 < 16) {
            const float* xn = xrow + (c + 3) * 64;
            aq[c % 3][0] = *(const float4*)(xn);
            aq[c % 3][1] = *(const float4*)(xn + 4);
            aq[c % 3][2] = *(const float4*)(xn + 32);
            aq[c % 3][3] = *(const float4*)(xn + 36);
        }

#pragma unroll
        for (int nt = 0; nt < 8; ++nt) {
            acc[nt] = __builtin_amdgcn_mfma_f32_16x16x32_bf16(af0, bfr[c & 1][nt * 2 + 0], acc[nt], 0, 0, 0);
            acc[nt] = __builtin_amdgcn_mfma_f32_16x16x32_bf16(af1, bfr[c & 1][nt * 2 + 1], acc[nt], 0, 0, 0);
        }
    }

    // acc -> vm_s: lane holds (row=kg*4+r, h=nt*16+m); rows consecutive -> b128
#pragma unroll
    for (int nt = 0; nt < 8; ++nt) {
        *(float4*)&vm_s[wave][nt * 16 + m][kg * 4] =
            make_float4(acc[nt][0], acc[nt][1], acc[nt][2], acc[nt][3]);
    }
    __syncthreads();

    // ---- Phase 2: combine. lane (i=lane>>4, j=lane&15); h = 4*tt + i. ----
    const int i = lane >> 4;
    const int j = lane & 15;

    float biasr[8];
#pragma unroll
    for (int s = 0; s < 4; ++s) {
        float2 bp = *(const float2*)(bias + 2 * j + 32 * s);
        biasr[2 * s] = bp.x; biasr[2 * s + 1] = bp.y;
    }
    int colb[4];
#pragma unroll
    for (int s = 0; s < 4; ++s) colb[s] = ((2 * j + 32 * s + 16 * i) & 127) * 2;
    const char* covb = (const char*)cov_s;

#pragma unroll 1
    for (int bb = 0; bb < 8; ++bb) {
        float op[8] = {0.f, 0.f, 0.f, 0.f, 0.f, 0.f, 0.f, 0.f};
#pragma unroll 4
        for (int tt = 0; tt < 32; ++tt) {
            int h = 4 * tt + i;
            float2 vmv = *(const float2*)&vm_s[wave][h][2 * bb];   // (v, m)
            float mval = vmv.y;
            int rb = h * 256;
            float p[8];
            float ls = 0.f;
#pragma unroll
            for (int s = 0; s < 4; ++s) {
                unsigned cc = *(const unsigned*)(covb + rb + colb[s]);
                union { unsigned u; _Float16 hx[2]; } cu; cu.u = cc;
                float p0 = __builtin_amdgcn_exp2f(mval * (float)cu.hx[0]);
                float p1 = __builtin_amdgcn_exp2f(mval * (float)cu.hx[1]);
                p[2 * s] = p0; p[2 * s + 1] = p1;
                ls += p0 + p1;
            }
            ls += __shfl_xor(ls, 1, 16);
            ls += __shfl_xor(ls, 2, 16);
            ls += __shfl_xor(ls, 4, 16);
            ls += __shfl_xor(ls, 8, 16);
            float w = vmv.x * __builtin_amdgcn_rcpf(ls);
#pragma unroll
            for (int u = 0; u < 8; ++u) op[u] = fmaf(w, p[u], op[u]);
        }
        // reduce over i-groups (lane bits 4-5)
#pragma unroll
        for (int u = 0; u < 8; ++u) {
            op[u] += __shfl_xor(op[u], 16, 64);
            op[u] += __shfl_xor(op[u], 32, 64);
        }
        if (lane < 16) {
            long b = (long)blockIdx.x * 32 + wave * 8 + bb;
            float* ob = out + b * 128;
#pragma unroll
            for (int s = 0; s < 4; ++s) {
                float2 o2;
                o2.x = op[2 * s] + biasr[2 * s];
                o2.y = op[2 * s + 1] + biasr[2 * s + 1];
                *(float2*)(ob + 2 * j + 32 * s) = o2;
            }
        }
    }
}

extern "C" void kernel_launch(void* const* d_in, const int* in_sizes, int n_in,
                              void* d_out, int out_size, void* d_ws, size_t ws_size,
                              hipStream_t stream) {
    const float* x    = (const float*)d_in[0];
    const float* W    = (const float*)d_in[1];
    const float* cov  = (const float*)d_in[2];
    const float* bias = (const float*)d_in[3];
    float* out = (float*)d_out;

    const int B = in_sizes[0] / (2 * 1024);   // 16384

    short* wbf = (short*)d_ws;                                  // [128*1024] bf16 frag order
    unsigned short* covh = (unsigned short*)(wbf + 128 * 1024); // [128*128] f16 rotated

    prep_kernel<<<65, 256, 0, stream>>>(W, cov, wbf, covh);

    const int blocks = (2 * B) / 64;          // 64 rows (=32 b) per block -> 512
    fused_kernel<<<blocks, 256, 0, stream>>>(x, wbf, covh, bias, out);
}

// Round 6
// 276.611 us; speedup vs baseline: 1.8906x; 1.0384x over previous
//
#include <hip/hip_runtime.h>
#include <hip/hip_bf16.h>

#define LOG2E 1.4426950408889634f

typedef __attribute__((ext_vector_type(8))) short frag_ab;   // 8 bf16 (4 VGPRs)
typedef __attribute__((ext_vector_type(4))) float frag_cd;   // 4 fp32 acc

// fp32 -> bf16 bits, round-to-nearest-even (inputs finite)
__device__ inline short f2bf(float f) {
    union { float f; unsigned u; } v; v.f = f;
    unsigned r = v.u + 0x7fffu + ((v.u >> 16) & 1u);
    return (short)(r >> 16);
}

// Blocks 0..63: W[128][1024] fp32 -> wbf bf16 in MFMA fragment order:
//   (h,k): c=k>>6, s=(k>>5)&1, kg=(k>>3)&3, j=k&7, nt=h>>4, m=h&15,
//   lane=kg*16+m -> wbf[(((c*8+nt)*2+s)*64+lane)*8 + j]
// Block 64: covh[h][k] = f16(cov[h][k]*log2e)  (plain layout; read via L1)
__global__ __launch_bounds__(256) void prep_kernel(const float* __restrict__ W,
                                                   const float* __restrict__ cov,
                                                   short* __restrict__ wbf,
                                                   unsigned short* __restrict__ covh) {
    if (blockIdx.x < 64) {
        int g = blockIdx.x * 256 + threadIdx.x;   // 0..16383
        int h = g >> 7;
        int k0 = (g & 127) << 3;
        const float* src = W + h * 1024 + k0;
        float4 w0 = *(const float4*)src;
        float4 w1 = *(const float4*)(src + 4);
        frag_ab af;
        af[0] = f2bf(w0.x); af[1] = f2bf(w0.y); af[2] = f2bf(w0.z); af[3] = f2bf(w0.w);
        af[4] = f2bf(w1.x); af[5] = f2bf(w1.y); af[6] = f2bf(w1.z); af[7] = f2bf(w1.w);
        int c = k0 >> 6, s = (k0 >> 5) & 1, kg = (k0 >> 3) & 3;
        int nt = h >> 4, m = h & 15, lane = kg * 16 + m;
        int dst = (((c * 8 + nt) * 2 + s) * 64 + lane) * 8;
        *(frag_ab*)(wbf + dst) = af;
    } else {
        int t = threadIdx.x;                      // 256 threads, 16384 elems
        for (int e = t; e < 16384; e += 256) {
            float c = cov[e] * LOG2E;
            union { _Float16 hf; unsigned short us; } cu;
            cu.hf = (_Float16)c;
            covh[e] = cu.us;
        }
    }
}

// Fused, TLP-oriented. Block = 512 thr (8 waves), owns 64 x-rows = 32 b's.
// Phase 1: wave w (w4=w&3, half=w>>2) computes rows [w4*16,w4*16+16) x 128 h
//   over k-half [half*512, half*512+512) -> 8 chunks of 64. Barrier-free;
//   A 3-chunk reg queue, B loaded per-use (L1/L2-hot frag order). 16 waves/CU
//   hide latency by TLP (each wave needs only ~1 outstanding 1KB load).
// Merge: waves 0-3 write vm_s, barrier, waves 4-7 add, barrier.
// Phase 2: each wave softmax-combines 4 b's (barrier-free). cov read from
//   global (L1-resident 32 KB f16). Softmax max-shift cancels algebraically.
__global__ __launch_bounds__(512, 4) void fused_kernel(const float* __restrict__ x,
                                                       const short* __restrict__ wbf,
                                                       const unsigned short* __restrict__ covh,
                                                       const float* __restrict__ bias,
                                                       float* __restrict__ out) {
    __shared__ __align__(16) float vm_s[128][68];   // [h][row], pad 68 -> <=2-way banks

    const int tid = threadIdx.x;
    const int lane = tid & 63, wave = tid >> 6;
    const int w4 = wave & 3, half = wave >> 2;
    const int m = lane & 15, kg = lane >> 4;
    const long rowbase = (long)blockIdx.x * 64 + w4 * 16;
    const float* xrow = x + (rowbase + m) * 1024 + half * 512 + kg * 8;
    const char* wb = (const char*)wbf + (size_t)half * 8 * 16384 + lane * 16;

    frag_cd acc[8];
#pragma unroll
    for (int nt = 0; nt < 8; ++nt) acc[nt] = (frag_cd){0.f, 0.f, 0.f, 0.f};

    float4 aq[3][4];
#pragma unroll
    for (int pc = 0; pc < 3; ++pc) {
        const float* xn = xrow + pc * 64;
        aq[pc][0] = *(const float4*)(xn);
        aq[pc][1] = *(const float4*)(xn + 4);
        aq[pc][2] = *(const float4*)(xn + 32);
        aq[pc][3] = *(const float4*)(xn + 36);
    }

#pragma unroll
    for (int c = 0; c < 8; ++c) {
        float4 a0 = aq[c % 3][0], a1 = aq[c % 3][1];
        float4 a2 = aq[c % 3][2], a3 = aq[c % 3][3];
        if (c + 3 < 8) {
            const float* xn = xrow + (c + 3) * 64;
            aq[c % 3][0] = *(const float4*)(xn);
            aq[c % 3][1] = *(const float4*)(xn + 4);
            aq[c % 3][2] = *(const float4*)(xn + 32);
            aq[c % 3][3] = *(const float4*)(xn + 36);
        }
        frag_ab af0, af1;
        af0[0] = f2bf(a0.x); af0[1] = f2bf(a0.y); af0[2] = f2bf(a0.z); af0[3] = f2bf(a0.w);
        af0[4] = f2bf(a1.x); af0[5] = f2bf(a1.y); af0[6] = f2bf(a1.z); af0[7] = f2bf(a1.w);
        af1[0] = f2bf(a2.x); af1[1] = f2bf(a2.y); af1[2] = f2bf(a2.z); af1[3] = f2bf(a2.w);
        af1[4] = f2bf(a3.x); af1[5] = f2bf(a3.y); af1[6] = f2bf(a3.z); af1[7] = f2bf(a3.w);

        const char* bc = wb + c * 16384;
#pragma unroll
        for (int nt = 0; nt < 8; ++nt) {
            frag_ab bf0 = *(const frag_ab*)(bc + (nt * 2 + 0) * 1024);
            frag_ab bf1 = *(const frag_ab*)(bc + (nt * 2 + 1) * 1024);
            acc[nt] = __builtin_amdgcn_mfma_f32_16x16x32_bf16(af0, bf0, acc[nt], 0, 0, 0);
            acc[nt] = __builtin_amdgcn_mfma_f32_16x16x32_bf16(af1, bf1, acc[nt], 0, 0, 0);
        }
    }

    // merge k-halves: lane holds (row=w4*16+kg*4+r, h=nt*16+m)
    if (half == 0) {
#pragma unroll
        for (int nt = 0; nt < 8; ++nt)
            *(float4*)&vm_s[nt * 16 + m][w4 * 16 + kg * 4] =
                make_float4(acc[nt][0], acc[nt][1], acc[nt][2], acc[nt][3]);
    }
    __syncthreads();
    if (half == 1) {
#pragma unroll
        for (int nt = 0; nt < 8; ++nt) {
            float4* p = (float4*)&vm_s[nt * 16 + m][w4 * 16 + kg * 4];
            float4 v = *p;
            v.x += acc[nt][0]; v.y += acc[nt][1]; v.z += acc[nt][2]; v.w += acc[nt][3];
            *p = v;
        }
    }
    __syncthreads();

    // ---- Phase 2: wave handles b-locals wave*4..wave*4+3 ----
    const int i = lane >> 4;   // h sub-index: h = 4*tt + i
    const int j = lane & 15;   // k-lane

    float biasr[8];
#pragma unroll
    for (int s = 0; s < 4; ++s) {
        float2 bp = *(const float2*)(bias + 2 * j + 32 * s);
        biasr[2 * s] = bp.x; biasr[2 * s + 1] = bp.y;
    }

#pragma unroll 1
    for (int q = 0; q < 4; ++q) {
        const int bl = wave * 4 + q;            // 0..31
        float op[8] = {0.f, 0.f, 0.f, 0.f, 0.f, 0.f, 0.f, 0.f};
#pragma unroll 4
        for (int tt = 0; tt < 32; ++tt) {
            int h = 4 * tt + i;
            float2 vmv = *(const float2*)&vm_s[h][2 * bl];   // (values, mask)
            float mval = vmv.y;
            const unsigned short* cr = covh + h * 128 + 2 * j;
            float p[8];
            float ls = 0.f;
#pragma unroll
            for (int s = 0; s < 4; ++s) {
                unsigned cc = *(const unsigned*)(cr + 32 * s);
                union { unsigned u; _Float16 hx[2]; } cu; cu.u = cc;
                float p0 = __builtin_amdgcn_exp2f(mval * (float)cu.hx[0]);
                float p1 = __builtin_amdgcn_exp2f(mval * (float)cu.hx[1]);
                p[2 * s] = p0; p[2 * s + 1] = p1;
                ls += p0 + p1;
            }
            ls += __shfl_xor(ls, 1, 16);
            ls += __shfl_xor(ls, 2, 16);
            ls += __shfl_xor(ls, 4, 16);
            ls += __shfl_xor(ls, 8, 16);
            float w = vmv.x * __builtin_amdgcn_rcpf(ls);
#pragma unroll
            for (int u = 0; u < 8; ++u) op[u] = fmaf(w, p[u], op[u]);
        }
#pragma unroll
        for (int u = 0; u < 8; ++u) {
            op[u] += __shfl_xor(op[u], 16, 64);
            op[u] += __shfl_xor(op[u], 32, 64);
        }
        if (lane < 16) {
            long b = (long)blockIdx.x * 32 + bl;
            float* ob = out + b * 128;
#pragma unroll
            for (int s = 0; s < 4; ++s) {
                float2 o2;
                o2.x = op[2 * s] + biasr[2 * s];
                o2.y = op[2 * s + 1] + biasr[2 * s + 1];
                *(float2*)(ob + 2 * j + 32 * s) = o2;
            }
        }
    }
}

extern "C" void kernel_launch(void* const* d_in, const int* in_sizes, int n_in,
                              void* d_out, int out_size, void* d_ws, size_t ws_size,
                              hipStream_t stream) {
    const float* x    = (const float*)d_in[0];
    const float* W    = (const float*)d_in[1];
    const float* cov  = (const float*)d_in[2];
    const float* bias = (const float*)d_in[3];
    float* out = (float*)d_out;

    const int B = in_sizes[0] / (2 * 1024);   // 16384

    short* wbf = (short*)d_ws;                                  // [128*1024] bf16 frag order
    unsigned short* covh = (unsigned short*)(wbf + 128 * 1024); // [128*128] f16 * log2e

    prep_kernel<<<65, 256, 0, stream>>>(W, cov, wbf, covh);

    const int blocks = (2 * B) / 64;          // 64 rows (=32 b) per block -> 512
    fused_kernel<<<blocks, 512, 0, stream>>>(x, wbf, covh, bias, out);
}